// Round 3
// baseline (18.242 us; speedup 1.0000x reference)
//
#include <hip/hip_runtime.h>

// Problem constants (from reference)
#define B_    2
#define H1_   64
#define W1_   96
#define H2_   64
#define W2_   96
#define HW_   (H1_ * W1_)          // 6144, also H2*W2
#define KWIN  81                   // 9x9 lookup window
#define CORR_ELEMS (B_ * KWIN * HW_)              // 995328
#define UP_HW      (8 * H1_ * 8 * W1_)            // 512*768

#define CORR_PIX    (B_ * HW_)                    // 12288 pixels
#define CORR_BLOCKS (CORR_PIX / 64)               // 192 blocks, 64 pixels x 4 q-groups
#define UP_THREADS  (B_ * H1_ * 8 * W1_)          // 98304 (n,h,r,w); 8 s per thread
#define UP_BLOCKS   (UP_THREADS / 256)            // 384
#define TOT_BLOCKS  (CORR_BLOCKS + UP_BLOCKS)     // 576

// One q-group of the 9x9 window for one pixel.
// Loads patch rows [R0, R0+NR) x 10 cols, computes q in [Q0, Q0+NQ) x p in [0,9).
template<int R0, int NR, int Q0, int NQ>
__device__ __forceinline__ void corr_part(const float* __restrict__ cm,
                                          int xi0, int yi0,
                                          float w00, float w10, float w01, float w11,
                                          float* __restrict__ out, size_t obase) {
    float P[NR][10];
#pragma unroll
    for (int r = 0; r < NR; ++r) {
        int y  = yi0 + R0 + r;
        bool vy = (y >= 0) & (y < H2_);
        int yc = min(max(y, 0), H2_ - 1);
        const float* rowp = cm + yc * W2_;
#pragma unroll
        for (int c = 0; c < 10; ++c) {
            int x  = xi0 + c;
            bool vx = (x >= 0) & (x < W2_);
            int xc = min(max(x, 0), W2_ - 1);
            float v = rowp[xc];
            P[r][c] = (vx & vy) ? v : 0.0f;
        }
    }
#pragma unroll
    for (int p = 0; p < 9; ++p) {
#pragma unroll
        for (int qq = 0; qq < NQ; ++qq) {
            int q  = Q0 + qq;
            int rr = q - R0;
            float val = w00 * P[rr][p]     + w10 * P[rr][p + 1]
                      + w01 * P[rr + 1][p] + w11 * P[rr + 1][p + 1];
            out[obase + (size_t)(p * 9 + q) * HW_] = val;       // 256B wave-store
        }
    }
}

// ---------------------------------------------------------------------------
// Fused kernel, 256-thread blocks.
//  blocks [0, CORR_BLOCKS): corr — 64 pixels/block, 4 waves = 4 q-groups
//  blocks [CORR_BLOCKS, TOT_BLOCKS): convex upsample — thread per (n,h,r,w)
// ---------------------------------------------------------------------------
__global__ __launch_bounds__(256) void fused_kernel(const float* __restrict__ cost,
                                                    const float* __restrict__ coords,
                                                    const float* __restrict__ flow,
                                                    const float* __restrict__ mask,
                                                    float* __restrict__ out) {
    if (blockIdx.x < CORR_BLOCKS) {
        // ---------------- corr ----------------
        int lane = threadIdx.x & 63;
        int g    = threadIdx.x >> 6;                 // q-group, wave-uniform
        int m    = blockIdx.x * 64 + lane;           // pixel id in [0, 12288)
        int b    = m / HW_;
        int rem  = m - b * HW_;

        float cx = coords[b * 2 * HW_ + rem];
        float cy = coords[b * 2 * HW_ + HW_ + rem];
        float xf = floorf(cx), yf = floorf(cy);
        float wx = cx - xf,   wy = cy - yf;
        int xi0 = (int)xf - 4;
        int yi0 = (int)yf - 4;

        float w00 = (1.0f - wx) * (1.0f - wy);
        float w10 = wx * (1.0f - wy);
        float w01 = (1.0f - wx) * wy;
        float w11 = wx * wy;

        const float* __restrict__ cm = cost + (size_t)m * HW_;   // map n == m
        size_t obase = (size_t)b * KWIN * HW_ + rem;

        if (g == 0)      corr_part<0, 4, 0, 3>(cm, xi0, yi0, w00, w10, w01, w11, out, obase);
        else if (g == 1) corr_part<3, 3, 3, 2>(cm, xi0, yi0, w00, w10, w01, w11, out, obase);
        else if (g == 2) corr_part<5, 3, 5, 2>(cm, xi0, yi0, w00, w10, w01, w11, out, obase);
        else             corr_part<7, 3, 7, 2>(cm, xi0, yi0, w00, w10, w01, w11, out, obase);
    } else {
        // ---------------- convex upsample ----------------
        int t = (blockIdx.x - CORR_BLOCKS) * 256 + threadIdx.x;  // [0, 98304)
        int w = t % W1_;
        int u = t / W1_;
        int r = u % 8; u /= 8;
        int h = u % H1_;
        int n = u / H1_;

        // mask: [B, 576, H1, W1]; channel = k*64 + r*8 + s
        const float* __restrict__ mp = mask + ((size_t)n * 576 + r * 8) * HW_ + h * W1_ + w;
        float mv[9][8];
#pragma unroll
        for (int k = 0; k < 9; ++k)
#pragma unroll
            for (int s = 0; s < 8; ++s)
                mv[k][s] = mp[(size_t)(k * 64 + s) * HW_];       // coalesced in w

        float scale[8];
#pragma unroll
        for (int s = 0; s < 8; ++s) {
            float mx = mv[0][s];
#pragma unroll
            for (int k = 1; k < 9; ++k) mx = fmaxf(mx, mv[k][s]);
            float sum = 0.0f;
#pragma unroll
            for (int k = 0; k < 9; ++k) { mv[k][s] = __expf(mv[k][s] - mx); sum += mv[k][s]; }
            scale[s] = 8.0f / sum;
        }

        const float* __restrict__ f0p = flow + (size_t)n * 2 * HW_;
        const float* __restrict__ f1p = f0p + HW_;
        float a0[8], a1[8];
#pragma unroll
        for (int s = 0; s < 8; ++s) { a0[s] = 0.0f; a1[s] = 0.0f; }

#pragma unroll
        for (int di = 0; di < 3; ++di) {
#pragma unroll
            for (int dj = 0; dj < 3; ++dj) {
                int k = di * 3 + dj;
                int hh = h + di - 1, ww = w + dj - 1;
                bool ok = (hh >= 0) & (hh < H1_) & (ww >= 0) & (ww < W1_);
                float fv0 = ok ? f0p[hh * W1_ + ww] : 0.0f;
                float fv1 = ok ? f1p[hh * W1_ + ww] : 0.0f;
#pragma unroll
                for (int s = 0; s < 8; ++s) {
                    a0[s] += mv[k][s] * fv0;
                    a1[s] += mv[k][s] * fv1;
                }
            }
        }

        float* outU = out + CORR_ELEMS;
        size_t ob = ((size_t)(n * 2 + 0) * (8 * H1_) + h * 8 + r) * (8 * W1_) + (size_t)w * 8;
        float4 c0a = make_float4(a0[0] * scale[0], a0[1] * scale[1], a0[2] * scale[2], a0[3] * scale[3]);
        float4 c0b = make_float4(a0[4] * scale[4], a0[5] * scale[5], a0[6] * scale[6], a0[7] * scale[7]);
        float4 c1a = make_float4(a1[0] * scale[0], a1[1] * scale[1], a1[2] * scale[2], a1[3] * scale[3]);
        float4 c1b = make_float4(a1[4] * scale[4], a1[5] * scale[5], a1[6] * scale[6], a1[7] * scale[7]);
        *(float4*)(outU + ob)              = c0a;
        *(float4*)(outU + ob + 4)          = c0b;
        *(float4*)(outU + ob + UP_HW)      = c1a;
        *(float4*)(outU + ob + UP_HW + 4)  = c1b;
    }
}

extern "C" void kernel_launch(void* const* d_in, const int* in_sizes, int n_in,
                              void* d_out, int out_size, void* d_ws, size_t ws_size,
                              hipStream_t stream) {
    const float* cost   = (const float*)d_in[0];   // [12288, 1, 64, 96]
    const float* coords = (const float*)d_in[1];   // [2, 2, 64, 96]
    const float* flow   = (const float*)d_in[2];   // [2, 2, 64, 96]
    const float* mask   = (const float*)d_in[3];   // [2, 576, 64, 96]
    float* out = (float*)d_out;                    // corr (995328) ++ up_flow (1572864)

    fused_kernel<<<TOT_BLOCKS, 256, 0, stream>>>(cost, coords, flow, mask, out);
}

// Round 4
// 16.470 us; speedup vs baseline: 1.1076x; 1.1076x over previous
//
#include <hip/hip_runtime.h>

// Problem constants (from reference)
#define B_    2
#define H1_   64
#define W1_   96
#define H2_   64
#define W2_   96
#define HW_   (H1_ * W1_)          // 6144, also H2*W2
#define KWIN  81                   // 9x9 lookup window
#define CORR_ELEMS (B_ * KWIN * HW_)              // 995328
#define UP_HW      (8 * H1_ * 8 * W1_)            // 512*768

#define CORR_PIX    (B_ * HW_)                    // 12288 pixels
#define CORR_BLOCKS (CORR_PIX / 64)               // 192 blocks, 64 pixels each
#define UP_THREADS  (B_ * H1_ * 8 * W1_)          // 98304 (n,h,r,w); 8 s per thread
#define UP_BLOCKS   (UP_THREADS / 256)            // 384
#define TOT_BLOCKS  (CORR_BLOCKS + UP_BLOCKS)     // 576

#define PSTRIDE 101                               // LDS stride per pixel (coprime w/ 32)

// ---------------------------------------------------------------------------
// Fused kernel, 256-thread blocks.
//  blocks [0, CORR_BLOCKS): corr — 64 pixels/block, LDS-staged two-phase
//  blocks [CORR_BLOCKS, TOT_BLOCKS): convex upsample — thread per (n,h,r,w)
// ---------------------------------------------------------------------------
__global__ __launch_bounds__(256) void fused_kernel(const float* __restrict__ cost,
                                                    const float* __restrict__ coords,
                                                    const float* __restrict__ flow,
                                                    const float* __restrict__ mask,
                                                    float* __restrict__ out) {
    __shared__ float patch[64 * PSTRIDE];          // 25.9 KB
    __shared__ int   xi0s[64];
    __shared__ int   yi0s[64];

    if (blockIdx.x < CORR_BLOCKS) {
        // ---------------- corr ----------------
        int tid  = threadIdx.x;
        int lane = tid & 63;
        int g    = tid >> 6;                        // wave id, 0..3
        int m    = blockIdx.x * 64 + lane;          // this lane's pixel (phase 0/2)
        int b    = m / HW_;                         // uniform per block (96 blocks/b)
        int rem  = m - b * HW_;

        // phase 0: per-pixel params (all 4 waves compute the same, lane=px)
        float cx = coords[b * 2 * HW_ + rem];
        float cy = coords[b * 2 * HW_ + HW_ + rem];
        float xf = floorf(cx), yf = floorf(cy);
        float wx = cx - xf,   wy = cy - yf;
        int xi0 = (int)xf - 4;
        int yi0 = (int)yf - 4;
        float w00 = (1.0f - wx) * (1.0f - wy);
        float w10 = wx * (1.0f - wy);
        float w01 = (1.0f - wx) * wy;
        float w11 = wx * wy;

        if (tid < 64) { xi0s[tid] = xi0; yi0s[tid] = yi0; }
        __syncthreads();

        // phase 1: cooperative patch load — 64 px * 100 elems = 6400 = 25*256
        const float* __restrict__ cmB = cost + (size_t)blockIdx.x * 64 * HW_;
#pragma unroll
        for (int it = 0; it < 25; ++it) {
            unsigned l  = it * 256u + tid;
            unsigned px = l / 100u;
            unsigned e  = l - px * 100u;
            unsigned r  = e / 10u;
            unsigned c  = e - r * 10u;
            int y = yi0s[px] + (int)r;
            int x = xi0s[px] + (int)c;
            bool ok = (x >= 0) & (x < W2_) & (y >= 0) & (y < H2_);
            int yc = min(max(y, 0), H2_ - 1);
            int xc = min(max(x, 0), W2_ - 1);
            float v = cmB[px * HW_ + yc * W2_ + xc];
            patch[px * PSTRIDE + e] = ok ? v : 0.0f;
        }
        __syncthreads();

        // phase 2: wave g computes contiguous channel chunk; lane = pixel
        const float* __restrict__ pp = patch + lane * PSTRIDE;
        size_t obase = (size_t)b * KWIN * HW_ + rem;
        int start = (g == 0) ? 0 : (1 + 20 * g);    // 0,21,41,61
        int count = (g == 0) ? 21 : 20;
        for (int t = 0; t < count; ++t) {
            int ch = start + t;                      // wave-uniform
            int p  = ch / 9;
            int q  = ch - p * 9;
            int o  = q * 10 + p;
            float val = w00 * pp[o]      + w10 * pp[o + 1]
                      + w01 * pp[o + 10] + w11 * pp[o + 11];
            out[obase + (size_t)ch * HW_] = val;     // 256B wave-store
        }
    } else {
        // ---------------- convex upsample ----------------
        int t = (blockIdx.x - CORR_BLOCKS) * 256 + threadIdx.x;  // [0, 98304)
        int w = t % W1_;
        int u = t / W1_;
        int r = u % 8; u /= 8;
        int h = u % H1_;
        int n = u / H1_;

        // mask: [B, 576, H1, W1]; channel = k*64 + r*8 + s
        const float* __restrict__ mp = mask + ((size_t)n * 576 + r * 8) * HW_ + h * W1_ + w;
        float mv[9][8];
#pragma unroll
        for (int k = 0; k < 9; ++k)
#pragma unroll
            for (int s = 0; s < 8; ++s)
                mv[k][s] = mp[(size_t)(k * 64 + s) * HW_];       // coalesced in w

        float scale[8];
#pragma unroll
        for (int s = 0; s < 8; ++s) {
            float mx = mv[0][s];
#pragma unroll
            for (int k = 1; k < 9; ++k) mx = fmaxf(mx, mv[k][s]);
            float sum = 0.0f;
#pragma unroll
            for (int k = 0; k < 9; ++k) { mv[k][s] = __expf(mv[k][s] - mx); sum += mv[k][s]; }
            scale[s] = 8.0f / sum;
        }

        const float* __restrict__ f0p = flow + (size_t)n * 2 * HW_;
        const float* __restrict__ f1p = f0p + HW_;
        float a0[8], a1[8];
#pragma unroll
        for (int s = 0; s < 8; ++s) { a0[s] = 0.0f; a1[s] = 0.0f; }

#pragma unroll
        for (int di = 0; di < 3; ++di) {
#pragma unroll
            for (int dj = 0; dj < 3; ++dj) {
                int k = di * 3 + dj;
                int hh = h + di - 1, ww = w + dj - 1;
                bool ok = (hh >= 0) & (hh < H1_) & (ww >= 0) & (ww < W1_);
                float fv0 = ok ? f0p[hh * W1_ + ww] : 0.0f;
                float fv1 = ok ? f1p[hh * W1_ + ww] : 0.0f;
#pragma unroll
                for (int s = 0; s < 8; ++s) {
                    a0[s] += mv[k][s] * fv0;
                    a1[s] += mv[k][s] * fv1;
                }
            }
        }

        float* outU = out + CORR_ELEMS;
        size_t ob = ((size_t)(n * 2 + 0) * (8 * H1_) + h * 8 + r) * (8 * W1_) + (size_t)w * 8;
        float4 c0a = make_float4(a0[0] * scale[0], a0[1] * scale[1], a0[2] * scale[2], a0[3] * scale[3]);
        float4 c0b = make_float4(a0[4] * scale[4], a0[5] * scale[5], a0[6] * scale[6], a0[7] * scale[7]);
        float4 c1a = make_float4(a1[0] * scale[0], a1[1] * scale[1], a1[2] * scale[2], a1[3] * scale[3]);
        float4 c1b = make_float4(a1[4] * scale[4], a1[5] * scale[5], a1[6] * scale[6], a1[7] * scale[7]);
        *(float4*)(outU + ob)              = c0a;
        *(float4*)(outU + ob + 4)          = c0b;
        *(float4*)(outU + ob + UP_HW)      = c1a;
        *(float4*)(outU + ob + UP_HW + 4)  = c1b;
    }
}

extern "C" void kernel_launch(void* const* d_in, const int* in_sizes, int n_in,
                              void* d_out, int out_size, void* d_ws, size_t ws_size,
                              hipStream_t stream) {
    const float* cost   = (const float*)d_in[0];   // [12288, 1, 64, 96]
    const float* coords = (const float*)d_in[1];   // [2, 2, 64, 96]
    const float* flow   = (const float*)d_in[2];   // [2, 2, 64, 96]
    const float* mask   = (const float*)d_in[3];   // [2, 576, 64, 96]
    float* out = (float*)d_out;                    // corr (995328) ++ up_flow (1572864)

    fused_kernel<<<TOT_BLOCKS, 256, 0, stream>>>(cost, coords, flow, mask, out);
}